// Round 1
// 308.055 us; speedup vs baseline: 1.0448x; 1.0448x over previous
//
#include <hip/hip_runtime.h>
#include <math.h>

#define BB 8
#define SS 4096
#define HH 1024
#define ROWS (BB * HH)   // 8192
#define KTOP 8
#define NS 32            // s-chunks; pairs ws = ROWS*NS*8*8B = 16.8 MB
#define SC (SS / NS)     // 128 s per chunk
#define SCW (SC / 4)     // 32 s per thread (4 wave-subchunks per block)

// Branch-free insert of XD into descending sorted D[0..7] (top-8 of 9):
//   D[i] <- max(D[i], min(D[i-1], XD))
// 15 v_{min,max}_f64, dependency depth 2, no branches, no masks.
// Scores are embedded exactly in the double's high bits (f32->f64 exact);
// the value's f32 bits >> 2 live in the 29 free low mantissa bits, so the
// payload can never reorder two distinct f32 scores. t==0 gives score=-inf
// with payload 0 (still a clean -inf), value decodes to 0.
#define INSERTD(D, XD) do {                                               \
    const double _x = (XD);                                               \
    const double _n0 = fmax(D[0], _x);                                    \
    const double _n1 = fmax(D[1], fmin(D[0], _x));                        \
    const double _n2 = fmax(D[2], fmin(D[1], _x));                        \
    const double _n3 = fmax(D[3], fmin(D[2], _x));                        \
    const double _n4 = fmax(D[4], fmin(D[3], _x));                        \
    const double _n5 = fmax(D[5], fmin(D[4], _x));                        \
    const double _n6 = fmax(D[6], fmin(D[5], _x));                        \
    const double _n7 = fmax(D[7], fmin(D[6], _x));                        \
    D[0] = _n0; D[1] = _n1; D[2] = _n2; D[3] = _n3;                       \
    D[4] = _n4; D[5] = _n5; D[6] = _n6; D[7] = _n7;                       \
  } while (0)

// Kernel 1: per-(row, s-chunk) top-8 of log(relu(h)) + gumbel.
// Block = 64 rows x 4 wave-subchunks (thread = 32 elems), grid (NS, ROWS/64)
// = 4096 blocks. All 40 loads of a thread's chunk (8 gather-float4 gumbel +
// 32 strided hidden dwords) are issued upfront: one vmcnt wait per wave,
// gathers stay L1-resident, max MLP. Subchunk top-8s tree-merged in LDS.
__global__ __launch_bounds__(256) void topk_partial(
    const float* __restrict__ hidden, const float* __restrict__ gumbel,
    double* __restrict__ pairs) {
  __shared__ double lst[256 * 9];   // [slot=w*64+rl][j], pad 8->9

  const int tid = threadIdx.x;
  const int rl  = tid & 63;         // local row (lane)
  const int w   = tid >> 6;         // wave = s-subchunk
  const int sc  = blockIdx.x;
  const int rb  = blockIdx.y;       // 64-row block
  const int r   = rb * 64 + rl;
  const int b   = rb >> 4;          // 64-row blocks never straddle a b
  const int h0  = (rb & 15) << 6;
  const int s_base = sc * SC + w * SCW;

  const float4* __restrict__ gp =
      (const float4*)(gumbel + (size_t)r * SS + s_base);
  const float* __restrict__ hp =
      hidden + ((size_t)b * SS + s_base) * HH + h0 + rl;

  // bulk upfront load: whole 32-element chunk in flight at once
  float4 g[8];
#pragma unroll
  for (int i = 0; i < 8; ++i) g[i] = gp[i];
  float hv[32];
#pragma unroll
  for (int i = 0; i < 32; ++i) hv[i] = hp[(size_t)i * HH];

  double D[8];
#pragma unroll
  for (int i = 0; i < KTOP; ++i) D[i] = -(double)INFINITY;

#pragma unroll
  for (int k = 0; k < 8; ++k) {
    const float gg[4] = {g[k].x, g[k].y, g[k].z, g[k].w};
#pragma unroll
    for (int c = 0; c < 4; ++c) {
      const float t   = fmaxf(hv[k * 4 + c], 0.0f);
      const float scv = logf(t) + gg[c];   // logf(0) = -inf: never picked
      double xd = (double)scv;             // exact; low 29 mantissa bits 0
      xd = __longlong_as_double(__double_as_longlong(xd)
             | (long long)(__float_as_uint(t) >> 2));
      INSERTD(D, xd);
    }
  }

  // publish per-subchunk top-8
#pragma unroll
  for (int j = 0; j < KTOP; ++j) lst[(w * 64 + rl) * 9 + j] = D[j];
  __syncthreads();
  // stage 1: wave 0 merges list1, wave 2 merges list3
  if (w == 0 || w == 2) {
#pragma unroll
    for (int j = 0; j < KTOP; ++j) {
      const double xd = lst[((w + 1) * 64 + rl) * 9 + j];
      INSERTD(D, xd);
    }
    if (w == 2) {
#pragma unroll
      for (int j = 0; j < KTOP; ++j) lst[(2 * 64 + rl) * 9 + j] = D[j];
    }
  }
  __syncthreads();
  // stage 2: wave 0 merges merged23, writes row's chunk top-8 (64B contig)
  if (w == 0) {
#pragma unroll
    for (int j = 0; j < KTOP; ++j) {
      const double xd = lst[(2 * 64 + rl) * 9 + j];
      INSERTD(D, xd);
    }
    double* __restrict__ op = pairs + ((size_t)r * NS + sc) * KTOP;
#pragma unroll
    for (int j = 0; j < KTOP; ++j) op[j] = D[j];
  }
}

// Kernel 2: merge NS chunk top-8s per row -> pooled[r] = sum of top-8 values.
// 8 threads/row, each merges NS/8 contiguous chunks (256B contiguous reads),
// 3-level LDS tree. grid ROWS/32 = 256 blocks; block 256.
__global__ __launch_bounds__(256) void topk_merge(
    const double* __restrict__ pairs, float* __restrict__ pooled) {
  __shared__ double ls[256 * 9];    // [slot=rloc*8+q][j], padded
  const int tid  = threadIdx.x;
  const int rloc = tid >> 3;        // 0..31
  const int q    = tid & 7;         // chunk group
  const int r    = blockIdx.x * 32 + rloc;
  const int slot = rloc * 8 + q;

  double D[8];
#pragma unroll
  for (int i = 0; i < KTOP; ++i) D[i] = -(double)INFINITY;

  const int cpg = NS / 8;           // chunks per group
  const double2* __restrict__ p =
      (const double2*)(pairs + ((size_t)r * NS + q * cpg) * KTOP);
#pragma unroll
  for (int i = 0; i < cpg * KTOP / 2; ++i) {
    const double2 two = p[i];
    INSERTD(D, two.x);
    INSERTD(D, two.y);
  }
#pragma unroll
  for (int j = 0; j < KTOP; ++j) ls[slot * 9 + j] = D[j];
  __syncthreads();
  if ((q & 1) == 0) {               // level 1: (0,1)(2,3)(4,5)(6,7)
#pragma unroll
    for (int j = 0; j < KTOP; ++j) {
      const double xd = ls[(slot + 1) * 9 + j];
      INSERTD(D, xd);
    }
#pragma unroll
    for (int j = 0; j < KTOP; ++j) ls[slot * 9 + j] = D[j];
  }
  __syncthreads();
  if ((q & 3) == 0) {               // level 2: (0,2)(4,6)
#pragma unroll
    for (int j = 0; j < KTOP; ++j) {
      const double xd = ls[(slot + 2) * 9 + j];
      INSERTD(D, xd);
    }
#pragma unroll
    for (int j = 0; j < KTOP; ++j) ls[slot * 9 + j] = D[j];
  }
  __syncthreads();
  if (q == 0) {                     // level 3: (0,4) -> decode payloads, sum
#pragma unroll
    for (int j = 0; j < KTOP; ++j) {
      const double xd = ls[(slot + 4) * 9 + j];
      INSERTD(D, xd);
    }
    float sum = 0.0f;
#pragma unroll
    for (int j = 0; j < KTOP; ++j) {
      const unsigned int lo = (unsigned int)__double_as_longlong(D[j]);
      sum += __uint_as_float((lo & 0x1FFFFFFFu) << 2);
    }
    // all-zero rows: every slot stayed -inf -> payload 0 -> sum 0 (matches ref)
    pooled[r] = sum;
  }
}

// Kernel 3: out[b][j] = tanh(sum_h pooled[b][h] * W[j][h] + bias[j]).
__global__ __launch_bounds__(256) void linear_tanh(
    const float* __restrict__ pooled, const float* __restrict__ W,
    const float* __restrict__ bias, float* __restrict__ out) {
  __shared__ float lp[ROWS];  // 32 KB: full pooled
  const int tid = threadIdx.x;
#pragma unroll
  for (int i = 0; i < ROWS / 4 / 256; ++i)
    ((float4*)lp)[i * 256 + tid] = ((const float4*)pooled)[i * 256 + tid];
  __syncthreads();

  const int wave = tid >> 6;
  const int lane = tid & 63;
  const int j = blockIdx.x * 4 + wave;

  float acc[BB];
#pragma unroll
  for (int bb = 0; bb < BB; ++bb) acc[bb] = 0.0f;
#pragma unroll
  for (int k0 = 0; k0 < HH; k0 += 256) {
    const float4 w4 = *(const float4*)&W[(size_t)j * HH + k0 + lane * 4];
#pragma unroll
    for (int bb = 0; bb < BB; ++bb) {
      const float4 p4 = *(const float4*)&lp[bb * HH + k0 + lane * 4];
      acc[bb] += w4.x * p4.x + w4.y * p4.y + w4.z * p4.z + w4.w * p4.w;
    }
  }
#pragma unroll
  for (int bb = 0; bb < BB; ++bb) {
    float a = acc[bb];
    for (int off = 32; off > 0; off >>= 1) a += __shfl_down(a, off, 64);
    if (lane == 0) out[(size_t)bb * HH + j] = tanhf(a + bias[j]);
  }
}

extern "C" void kernel_launch(void* const* d_in, const int* in_sizes, int n_in,
                              void* d_out, int out_size, void* d_ws, size_t ws_size,
                              hipStream_t stream) {
  const float* hidden = (const float*)d_in[0];
  const float* gumbel = (const float*)d_in[1];
  const float* W      = (const float*)d_in[2];
  const float* bias   = (const float*)d_in[3];
  float* out          = (float*)d_out;

  double* pairs  = (double*)d_ws;
  float*  pooled = (float*)((char*)d_ws
                   + (size_t)ROWS * NS * KTOP * sizeof(double));

  topk_partial<<<dim3(NS, ROWS / 64), dim3(256), 0, stream>>>(hidden, gumbel, pairs);
  topk_merge<<<dim3(ROWS / 32), dim3(256), 0, stream>>>(pairs, pooled);
  linear_tanh<<<dim3(HH / 4), dim3(256), 0, stream>>>(pooled, W, bias, out);
}

// Round 2
// 301.693 us; speedup vs baseline: 1.0668x; 1.0211x over previous
//
#include <hip/hip_runtime.h>
#include <math.h>

#define BB 8
#define SS 4096
#define HH 1024
#define ROWS (BB * HH)   // 8192
#define KTOP 8
#define NS 32            // s-chunks; pairs ws = ROWS*NS*8*8B = 16.8 MB
#define SC (SS / NS)     // 128 s per chunk
#define SCW (SC / 4)     // 32 s per thread (4 wave-subchunks per block)

// Branch-free insert of XD into descending sorted D[0..7] (top-8 of 9):
//   D[i] <- max(D[i], min(D[i-1], XD))
// 15 v_{min,max}_f64, dependency depth 2, no branches, no masks.
// Scores are embedded exactly in the double's high bits (f32->f64 exact);
// the value's f32 bits >> 2 live in the 29 free low mantissa bits, so the
// payload can never reorder two distinct f32 scores. t==0 gives score=-inf
// with payload 0 (still a clean -inf), value decodes to 0.
#define INSERTD(D, XD) do {                                               \
    const double _x = (XD);                                               \
    const double _n0 = fmax(D[0], _x);                                    \
    const double _n1 = fmax(D[1], fmin(D[0], _x));                        \
    const double _n2 = fmax(D[2], fmin(D[1], _x));                        \
    const double _n3 = fmax(D[3], fmin(D[2], _x));                        \
    const double _n4 = fmax(D[4], fmin(D[3], _x));                        \
    const double _n5 = fmax(D[5], fmin(D[4], _x));                        \
    const double _n6 = fmax(D[6], fmin(D[5], _x));                        \
    const double _n7 = fmax(D[7], fmin(D[6], _x));                        \
    D[0] = _n0; D[1] = _n1; D[2] = _n2; D[3] = _n3;                       \
    D[4] = _n4; D[5] = _n5; D[6] = _n6; D[7] = _n7;                       \
  } while (0)

// Kernel 1: per-(row, s-chunk) top-8 of log(relu(h)) + gumbel.
// Block = 64 rows x 4 wave-subchunks (thread = 32 elems), grid (NS, ROWS/64)
// = 4096 blocks. All 40 loads of a thread's chunk (8 gather-float4 gumbel +
// 32 strided hidden dwords) are issued upfront and PINNED with
// sched_barrier(0) so the compiler cannot sink them to their uses (round-1
// showed VGPR=36 -> loads were sunk, MLP ~4, latency-bound at 23% HBM).
// Gumbel issues first so each element's wait drains only up to its own hv
// load (vmcnt(31-4k-c)), keeping the rest of the stream in flight.
__global__ __launch_bounds__(256, 4) void topk_partial(
    const float* __restrict__ hidden, const float* __restrict__ gumbel,
    double* __restrict__ pairs) {
  __shared__ double lst[256 * 9];   // [slot=w*64+rl][j], pad 8->9

  const int tid = threadIdx.x;
  const int rl  = tid & 63;         // local row (lane)
  const int w   = tid >> 6;         // wave = s-subchunk
  const int sc  = blockIdx.x;
  const int rb  = blockIdx.y;       // 64-row block
  const int r   = rb * 64 + rl;
  const int b   = rb >> 4;          // 64-row blocks never straddle a b
  const int h0  = (rb & 15) << 6;
  const int s_base = sc * SC + w * SCW;

  const float4* __restrict__ gp =
      (const float4*)(gumbel + (size_t)r * SS + s_base);
  const float* __restrict__ hp =
      hidden + ((size_t)b * SS + s_base) * HH + h0 + rl;

  // bulk upfront load: whole 32-element chunk in flight at once
  float4 g[8];
#pragma unroll
  for (int i = 0; i < 8; ++i) g[i] = gp[i];
  __builtin_amdgcn_sched_barrier(0);   // g-block issues first
  float hv[32];
#pragma unroll
  for (int i = 0; i < 32; ++i) hv[i] = hp[(size_t)i * HH];
  __builtin_amdgcn_sched_barrier(0);   // no load sinks into compute

  double D[8];
#pragma unroll
  for (int i = 0; i < KTOP; ++i) D[i] = -(double)INFINITY;

#pragma unroll
  for (int k = 0; k < 8; ++k) {
    const float gg[4] = {g[k].x, g[k].y, g[k].z, g[k].w};
#pragma unroll
    for (int c = 0; c < 4; ++c) {
      const float t   = fmaxf(hv[k * 4 + c], 0.0f);
      const float scv = logf(t) + gg[c];   // logf(0) = -inf: never picked
      double xd = (double)scv;             // exact; low 29 mantissa bits 0
      xd = __longlong_as_double(__double_as_longlong(xd)
             | (long long)(__float_as_uint(t) >> 2));
      INSERTD(D, xd);
    }
  }

  // publish per-subchunk top-8
#pragma unroll
  for (int j = 0; j < KTOP; ++j) lst[(w * 64 + rl) * 9 + j] = D[j];
  __syncthreads();
  // stage 1: wave 0 merges list1, wave 2 merges list3
  if (w == 0 || w == 2) {
#pragma unroll
    for (int j = 0; j < KTOP; ++j) {
      const double xd = lst[((w + 1) * 64 + rl) * 9 + j];
      INSERTD(D, xd);
    }
    if (w == 2) {
#pragma unroll
      for (int j = 0; j < KTOP; ++j) lst[(2 * 64 + rl) * 9 + j] = D[j];
    }
  }
  __syncthreads();
  // stage 2: wave 0 merges merged23, writes row's chunk top-8 (64B contig)
  if (w == 0) {
#pragma unroll
    for (int j = 0; j < KTOP; ++j) {
      const double xd = lst[(2 * 64 + rl) * 9 + j];
      INSERTD(D, xd);
    }
    double* __restrict__ op = pairs + ((size_t)r * NS + sc) * KTOP;
#pragma unroll
    for (int j = 0; j < KTOP; ++j) op[j] = D[j];
  }
}

// Kernel 2: merge NS chunk top-8s per row -> pooled[r] = sum of top-8 values.
// 8 threads/row, each merges NS/8 contiguous chunks (256B contiguous reads),
// 3-level LDS tree. grid ROWS/32 = 256 blocks; block 256.
__global__ __launch_bounds__(256) void topk_merge(
    const double* __restrict__ pairs, float* __restrict__ pooled) {
  __shared__ double ls[256 * 9];    // [slot=rloc*8+q][j], padded
  const int tid  = threadIdx.x;
  const int rloc = tid >> 3;        // 0..31
  const int q    = tid & 7;         // chunk group
  const int r    = blockIdx.x * 32 + rloc;
  const int slot = rloc * 8 + q;

  double D[8];
#pragma unroll
  for (int i = 0; i < KTOP; ++i) D[i] = -(double)INFINITY;

  const int cpg = NS / 8;           // chunks per group
  const double2* __restrict__ p =
      (const double2*)(pairs + ((size_t)r * NS + q * cpg) * KTOP);
#pragma unroll
  for (int i = 0; i < cpg * KTOP / 2; ++i) {
    const double2 two = p[i];
    INSERTD(D, two.x);
    INSERTD(D, two.y);
  }
#pragma unroll
  for (int j = 0; j < KTOP; ++j) ls[slot * 9 + j] = D[j];
  __syncthreads();
  if ((q & 1) == 0) {               // level 1: (0,1)(2,3)(4,5)(6,7)
#pragma unroll
    for (int j = 0; j < KTOP; ++j) {
      const double xd = ls[(slot + 1) * 9 + j];
      INSERTD(D, xd);
    }
#pragma unroll
    for (int j = 0; j < KTOP; ++j) ls[slot * 9 + j] = D[j];
  }
  __syncthreads();
  if ((q & 3) == 0) {               // level 2: (0,2)(4,6)
#pragma unroll
    for (int j = 0; j < KTOP; ++j) {
      const double xd = ls[(slot + 2) * 9 + j];
      INSERTD(D, xd);
    }
#pragma unroll
    for (int j = 0; j < KTOP; ++j) ls[slot * 9 + j] = D[j];
  }
  __syncthreads();
  if (q == 0) {                     // level 3: (0,4) -> decode payloads, sum
#pragma unroll
    for (int j = 0; j < KTOP; ++j) {
      const double xd = ls[(slot + 4) * 9 + j];
      INSERTD(D, xd);
    }
    float sum = 0.0f;
#pragma unroll
    for (int j = 0; j < KTOP; ++j) {
      const unsigned int lo = (unsigned int)__double_as_longlong(D[j]);
      sum += __uint_as_float((lo & 0x1FFFFFFFu) << 2);
    }
    // all-zero rows: every slot stayed -inf -> payload 0 -> sum 0 (matches ref)
    pooled[r] = sum;
  }
}

// Kernel 3: out[b][j] = tanh(sum_h pooled[b][h] * W[j][h] + bias[j]).
__global__ __launch_bounds__(256) void linear_tanh(
    const float* __restrict__ pooled, const float* __restrict__ W,
    const float* __restrict__ bias, float* __restrict__ out) {
  __shared__ float lp[ROWS];  // 32 KB: full pooled
  const int tid = threadIdx.x;
#pragma unroll
  for (int i = 0; i < ROWS / 4 / 256; ++i)
    ((float4*)lp)[i * 256 + tid] = ((const float4*)pooled)[i * 256 + tid];
  __syncthreads();

  const int wave = tid >> 6;
  const int lane = tid & 63;
  const int j = blockIdx.x * 4 + wave;

  float acc[BB];
#pragma unroll
  for (int bb = 0; bb < BB; ++bb) acc[bb] = 0.0f;
#pragma unroll
  for (int k0 = 0; k0 < HH; k0 += 256) {
    const float4 w4 = *(const float4*)&W[(size_t)j * HH + k0 + lane * 4];
#pragma unroll
    for (int bb = 0; bb < BB; ++bb) {
      const float4 p4 = *(const float4*)&lp[bb * HH + k0 + lane * 4];
      acc[bb] += w4.x * p4.x + w4.y * p4.y + w4.z * p4.z + w4.w * p4.w;
    }
  }
#pragma unroll
  for (int bb = 0; bb < BB; ++bb) {
    float a = acc[bb];
    for (int off = 32; off > 0; off >>= 1) a += __shfl_down(a, off, 64);
    if (lane == 0) out[(size_t)bb * HH + j] = tanhf(a + bias[j]);
  }
}

extern "C" void kernel_launch(void* const* d_in, const int* in_sizes, int n_in,
                              void* d_out, int out_size, void* d_ws, size_t ws_size,
                              hipStream_t stream) {
  const float* hidden = (const float*)d_in[0];
  const float* gumbel = (const float*)d_in[1];
  const float* W      = (const float*)d_in[2];
  const float* bias   = (const float*)d_in[3];
  float* out          = (float*)d_out;

  double* pairs  = (double*)d_ws;
  float*  pooled = (float*)((char*)d_ws
                   + (size_t)ROWS * NS * KTOP * sizeof(double));

  topk_partial<<<dim3(NS, ROWS / 64), dim3(256), 0, stream>>>(hidden, gumbel, pairs);
  topk_merge<<<dim3(ROWS / 32), dim3(256), 0, stream>>>(pairs, pooled);
  linear_tanh<<<dim3(HH / 4), dim3(256), 0, stream>>>(pooled, W, bias, out);
}